// Round 9
// baseline (101.030 us; speedup 1.0000x reference)
//
#include <hip/hip_runtime.h>

#define BN 8192
#define BD 256
#define NTRIALS 150

// EXACT R1/R4/R7/R8 reduce — proven bitwise-compatible with the reference four times.
__device__ __forceinline__ float wave_reduce_sum(float v) {
    #pragma unroll
    for (int m = 32; m > 0; m >>= 1) v += __shfl_xor(v, m, 64);
    return v;
}

// Kernel 1: count genuine (tgt == 0). Single block. (verbatim from passing rounds)
__global__ __launch_bounds__(1024) void count_genuine_kernel(
    const int* __restrict__ tgt, int* __restrict__ cnt)
{
    __shared__ int lds[16];
    const int t = threadIdx.x;
    int c = 0;
    for (int i = t; i < BN; i += 1024) c += (tgt[i] == 0) ? 1 : 0;
    #pragma unroll
    for (int m = 32; m > 0; m >>= 1) c += __shfl_xor(c, m, 64);
    if ((t & 63) == 0) lds[t >> 6] = c;
    __syncthreads();
    if (t == 0) {
        int s = 0;
        #pragma unroll
        for (int w = 0; w < 16; ++w) s += lds[w];
        *cnt = s;
    }
}

// Kernel 2: sq[i] = sum_d hd[i][d]^2. One wave per row. (verbatim from passing rounds)
__global__ __launch_bounds__(256) void sqnorm_kernel(
    const float* __restrict__ hd, float* __restrict__ sq)
{
    const int lane = threadIdx.x & 63;
    const int row  = blockIdx.x * 4 + (threadIdx.x >> 6);
    const float4 a = *reinterpret_cast<const float4*>(hd + row * BD + lane * 4);
    float s = a.x * a.x + a.y * a.y + a.z * a.z + a.w * a.w;
    s = wave_reduce_sum(s);
    if (lane == 0) sq[row] = s;
}

// Compute one trial's dn — BYTE-IDENTICAL text to passing R8. Unconditional
// prefetch of trial PFT into the same slot (caller guarantees PFT < NTRIALS).
#define TRIAL_COMPUTE_PF(CSLOT, BJSLOT, SQSLOT, PFT, CSAVE, DNSAVE)             \
    {                                                                           \
        const int    c_  = CSLOT;                                               \
        const float4 bj  = BJSLOT;                                              \
        const float  sqc = SQSLOT;                                              \
        {                                                                       \
            int c2 = (int)(unrow[PFT] * lnf);                                   \
            c2 = min(c2, lnm1);                                                 \
            CSLOT  = c2;                                                        \
            BJSLOT = *reinterpret_cast<const float4*>(hd + c2 * BD + lane * 4); \
            SQSLOT = sq[c2];                                                    \
        }                                                                       \
        float p = a.x * bj.x + a.y * bj.y + a.z * bj.z + a.w * bj.w;            \
        const float dn = (sqi - 2.0f * wave_reduce_sum(p)) + sqc;               \
        CSAVE  = c_;                                                            \
        DNSAVE = dn;                                                            \
    }

// Same compute text, no prefetch (final peeled group). (verbatim from R8)
#define TRIAL_COMPUTE_NP(CSLOT, BJSLOT, SQSLOT, CSAVE, DNSAVE)                  \
    {                                                                           \
        const int    c_  = CSLOT;                                               \
        const float4 bj  = BJSLOT;                                              \
        const float  sqc = SQSLOT;                                              \
        float p = a.x * bj.x + a.y * bj.y + a.z * bj.z + a.w * bj.w;            \
        const float dn = (sqi - 2.0f * wave_reduce_sum(p)) + sqc;               \
        CSAVE  = c_;                                                            \
        DNSAVE = dn;                                                            \
    }

// Branchless in-order selection. Same comparison expressions on the same bits
// as R8's TRIAL_CHECK; control construct replaced by selects:
//  - chosen := first trial (in order) with hit            (== argmax(cond))
//  - best/best_c := strict-< running min over ALL trials  (== argmin, first occ.;
//    post-hit updates are dead: fallback read only when no hit exists)
#define TRIAL_SEL(CSAVE, DNSAVE)                                                \
    {                                                                           \
        const float z = dst_pos - (DNSAVE);                                     \
        const bool hit  = (z < 0.0f) && ((z + margin) > 0.0f);                  \
        const bool take = hit && (chosen < 0);                                  \
        chosen = take ? (CSAVE) : chosen;                                       \
        const bool mn = (DNSAVE) < best;                                        \
        best_c = mn ? (CSAVE) : best_c;                                         \
        best   = mn ? (DNSAVE) : best;                                          \
    }

// Kernel 3: one wave per anchor; ALL 150 trials, uniform work, zero
// data-dependent control flow. Groups of 6 -> six independent shuffle chains
// per straight-line basic block.
__global__ __launch_bounds__(256) void triplet_kernel(
    const float* __restrict__ hd, const int* __restrict__ tgt,
    const float* __restrict__ margin_p, const float* __restrict__ u_pos,
    const float* __restrict__ u_neg, const float* __restrict__ sq,
    const int* __restrict__ cnt, float* __restrict__ out)
{
    const int lane = threadIdx.x & 63;
    const int i    = blockIdx.x * 4 + (threadIdx.x >> 6);

    // anchor row in registers (float4 per lane: 64*4 = 256 = D)
    const float4 a = *reinterpret_cast<const float4*>(hd + i * BD + lane * 4);
    const float sqi = sq[i];

    const int ng = *cnt;
    const int ti = tgt[i];
    const int len_pos = (ti == 0) ? ng : (BN - ng);
    const int len_neg = (ti == 0) ? (BN - ng) : ng;

    // positive index — exact integer/fp32 replication of the reference
    const bool excl = (i < len_pos);
    const int  eff  = len_pos - (excl ? 1 : 0);
    const float up  = u_pos[i];
    int u = (int)(up * (float)eff);        // fp32 multiply, trunc toward zero
    u = min(u, eff - 1);
    const int pos_idx = u + ((excl && (u >= i)) ? 1 : 0);

    // dst_pos = (sq_i - 2*dot) + sq_j  (same expression/order as all passing rounds)
    const float4 bp = *reinterpret_cast<const float4*>(hd + pos_idx * BD + lane * 4);
    float pp = a.x * bp.x + a.y * bp.y + a.z * bp.z + a.w * bp.w;
    const float dot_pos = wave_reduce_sum(pp);
    const float dst_pos = (sqi - 2.0f * dot_pos) + sq[pos_idx];

    // write anchor + positive rows now (overlaps with the scan)
    float* orow = out + i * (3 * BD);
    *reinterpret_cast<float4*>(orow + lane * 4) = a;
    *reinterpret_cast<float4*>(orow + BD + lane * 4) = bp;

    const float margin = margin_p[0];
    const float lnf    = (float)len_neg;
    const int   lnm1   = len_neg - 1;

    int   chosen = -1;
    float best   = __builtin_inff();
    int   best_c = 0;
    const float* unrow = u_neg + i * NTRIALS;

    // prologue: prefetch trials 0..5 into slots A..F
    int cA, cB, cC, cD, cE, cF;
    float4 bjA, bjB, bjC, bjD, bjE, bjF;
    float sqA, sqB, sqC, sqD, sqE, sqF;
#define PROLOGUE_SLOT(CS, BJS, SQS, T)                                          \
    {                                                                           \
        int c = (int)(unrow[T] * lnf);                                          \
        c = min(c, lnm1);                                                       \
        CS  = c;                                                                \
        BJS = *reinterpret_cast<const float4*>(hd + c * BD + lane * 4);         \
        SQS = sq[c];                                                            \
    }
    PROLOGUE_SLOT(cA, bjA, sqA, 0)
    PROLOGUE_SLOT(cB, bjB, sqB, 1)
    PROLOGUE_SLOT(cC, bjC, sqC, 2)
    PROLOGUE_SLOT(cD, bjD, sqD, 3)
    PROLOGUE_SLOT(cE, bjE, sqE, 4)
    PROLOGUE_SLOT(cF, bjF, sqF, 5)

    // main loop: t = 0,6,...,138 — computes trials t..t+5, prefetches t+6..t+11
    // (always in range; no data-dependent branches anywhere in the loop)
    for (int t = 0; t < NTRIALS - 6; t += 6) {
        int cs0, cs1, cs2, cs3, cs4, cs5;
        float dn0, dn1, dn2, dn3, dn4, dn5;
        TRIAL_COMPUTE_PF(cA, bjA, sqA, t + 6,  cs0, dn0)
        TRIAL_COMPUTE_PF(cB, bjB, sqB, t + 7,  cs1, dn1)
        TRIAL_COMPUTE_PF(cC, bjC, sqC, t + 8,  cs2, dn2)
        TRIAL_COMPUTE_PF(cD, bjD, sqD, t + 9,  cs3, dn3)
        TRIAL_COMPUTE_PF(cE, bjE, sqE, t + 10, cs4, dn4)
        TRIAL_COMPUTE_PF(cF, bjF, sqF, t + 11, cs5, dn5)
        TRIAL_SEL(cs0, dn0)
        TRIAL_SEL(cs1, dn1)
        TRIAL_SEL(cs2, dn2)
        TRIAL_SEL(cs3, dn3)
        TRIAL_SEL(cs4, dn4)
        TRIAL_SEL(cs5, dn5)
    }
    // peeled final group: trials 144..149 — no prefetch
    {
        int cs0, cs1, cs2, cs3, cs4, cs5;
        float dn0, dn1, dn2, dn3, dn4, dn5;
        TRIAL_COMPUTE_NP(cA, bjA, sqA, cs0, dn0)
        TRIAL_COMPUTE_NP(cB, bjB, sqB, cs1, dn1)
        TRIAL_COMPUTE_NP(cC, bjC, sqC, cs2, dn2)
        TRIAL_COMPUTE_NP(cD, bjD, sqD, cs3, dn3)
        TRIAL_COMPUTE_NP(cE, bjE, sqE, cs4, dn4)
        TRIAL_COMPUTE_NP(cF, bjF, sqF, cs5, dn5)
        TRIAL_SEL(cs0, dn0)
        TRIAL_SEL(cs1, dn1)
        TRIAL_SEL(cs2, dn2)
        TRIAL_SEL(cs3, dn3)
        TRIAL_SEL(cs4, dn4)
        TRIAL_SEL(cs5, dn5)
    }

    const int neg = (chosen >= 0) ? chosen : best_c;

    const float4 bn = *reinterpret_cast<const float4*>(hd + neg * BD + lane * 4);
    *reinterpret_cast<float4*>(orow + 2 * BD + lane * 4) = bn;
}

extern "C" void kernel_launch(void* const* d_in, const int* in_sizes, int n_in,
                              void* d_out, int out_size, void* d_ws, size_t ws_size,
                              hipStream_t stream) {
    const float* hd     = (const float*)d_in[0];
    const int*   tgt    = (const int*)d_in[1];
    const float* margin = (const float*)d_in[2];
    const float* u_pos  = (const float*)d_in[3];
    const float* u_neg  = (const float*)d_in[4];
    float* out = (float*)d_out;

    float* sq  = (float*)d_ws;
    int*   cnt = (int*)((char*)d_ws + BN * sizeof(float));

    count_genuine_kernel<<<1, 1024, 0, stream>>>(tgt, cnt);
    sqnorm_kernel<<<BN / 4, 256, 0, stream>>>(hd, sq);
    triplet_kernel<<<BN / 4, 256, 0, stream>>>(hd, tgt, margin, u_pos, u_neg, sq, cnt, out);
}

// Round 10
// 100.737 us; speedup vs baseline: 1.0029x; 1.0029x over previous
//
#include <hip/hip_runtime.h>

#define BN 8192
#define BD 256
#define NTRIALS 150

// EXACT R1/R4/R7/R8/R9 reduce — proven bitwise-compatible with the reference five times.
__device__ __forceinline__ float wave_reduce_sum(float v) {
    #pragma unroll
    for (int m = 32; m > 0; m >>= 1) v += __shfl_xor(v, m, 64);
    return v;
}

// Kernel 1: count genuine (tgt == 0). Single block. (verbatim from passing rounds)
__global__ __launch_bounds__(1024) void count_genuine_kernel(
    const int* __restrict__ tgt, int* __restrict__ cnt)
{
    __shared__ int lds[16];
    const int t = threadIdx.x;
    int c = 0;
    for (int i = t; i < BN; i += 1024) c += (tgt[i] == 0) ? 1 : 0;
    #pragma unroll
    for (int m = 32; m > 0; m >>= 1) c += __shfl_xor(c, m, 64);
    if ((t & 63) == 0) lds[t >> 6] = c;
    __syncthreads();
    if (t == 0) {
        int s = 0;
        #pragma unroll
        for (int w = 0; w < 16; ++w) s += lds[w];
        *cnt = s;
    }
}

// Kernel 2: sq[i] = sum_d hd[i][d]^2. One wave per row. (verbatim from passing rounds)
__global__ __launch_bounds__(256) void sqnorm_kernel(
    const float* __restrict__ hd, float* __restrict__ sq)
{
    const int lane = threadIdx.x & 63;
    const int row  = blockIdx.x * 4 + (threadIdx.x >> 6);
    const float4 a = *reinterpret_cast<const float4*>(hd + row * BD + lane * 4);
    float s = a.x * a.x + a.y * a.y + a.z * a.z + a.w * a.w;
    s = wave_reduce_sum(s);
    if (lane == 0) sq[row] = s;
}

// Compute one trial's dn — BYTE-IDENTICAL text to passing R8/R9. Unconditional
// prefetch of trial PFT into the same slot (caller guarantees PFT < NTRIALS).
#define TRIAL_COMPUTE_PF(CSLOT, BJSLOT, SQSLOT, PFT, CSAVE, DNSAVE)             \
    {                                                                           \
        const int    c_  = CSLOT;                                               \
        const float4 bj  = BJSLOT;                                              \
        const float  sqc = SQSLOT;                                              \
        {                                                                       \
            int c2 = (int)(unrow[PFT] * lnf);                                   \
            c2 = min(c2, lnm1);                                                 \
            CSLOT  = c2;                                                        \
            BJSLOT = *reinterpret_cast<const float4*>(hd + c2 * BD + lane * 4); \
            SQSLOT = sq[c2];                                                    \
        }                                                                       \
        float p = a.x * bj.x + a.y * bj.y + a.z * bj.z + a.w * bj.w;            \
        const float dn = (sqi - 2.0f * wave_reduce_sum(p)) + sqc;               \
        CSAVE  = c_;                                                            \
        DNSAVE = dn;                                                            \
    }

// Same compute text, no prefetch (final peeled group). (verbatim from R8/R9)
#define TRIAL_COMPUTE_NP(CSLOT, BJSLOT, SQSLOT, CSAVE, DNSAVE)                  \
    {                                                                           \
        const int    c_  = CSLOT;                                               \
        const float4 bj  = BJSLOT;                                              \
        const float  sqc = SQSLOT;                                              \
        float p = a.x * bj.x + a.y * bj.y + a.z * bj.z + a.w * bj.w;            \
        const float dn = (sqi - 2.0f * wave_reduce_sum(p)) + sqc;               \
        CSAVE  = c_;                                                            \
        DNSAVE = dn;                                                            \
    }

// Branchless in-order selection — BYTE-IDENTICAL to passing R9.
#define TRIAL_SEL(CSAVE, DNSAVE)                                                \
    {                                                                           \
        const float z = dst_pos - (DNSAVE);                                     \
        const bool hit  = (z < 0.0f) && ((z + margin) > 0.0f);                  \
        const bool take = hit && (chosen < 0);                                  \
        chosen = take ? (CSAVE) : chosen;                                       \
        const bool mn = (DNSAVE) < best;                                        \
        best_c = mn ? (CSAVE) : best_c;                                         \
        best   = mn ? (DNSAVE) : best;                                          \
    }

// Kernel 3: one wave per anchor; groups of 6 branchless trials (R9 structure)
// + ONE wave-uniform early-exit branch per group (chosen is lane-invariant).
__global__ __launch_bounds__(256) void triplet_kernel(
    const float* __restrict__ hd, const int* __restrict__ tgt,
    const float* __restrict__ margin_p, const float* __restrict__ u_pos,
    const float* __restrict__ u_neg, const float* __restrict__ sq,
    const int* __restrict__ cnt, float* __restrict__ out)
{
    const int lane = threadIdx.x & 63;
    const int i    = blockIdx.x * 4 + (threadIdx.x >> 6);

    // anchor row in registers (float4 per lane: 64*4 = 256 = D)
    const float4 a = *reinterpret_cast<const float4*>(hd + i * BD + lane * 4);
    const float sqi = sq[i];

    const int ng = *cnt;
    const int ti = tgt[i];
    const int len_pos = (ti == 0) ? ng : (BN - ng);
    const int len_neg = (ti == 0) ? (BN - ng) : ng;

    // positive index — exact integer/fp32 replication of the reference
    const bool excl = (i < len_pos);
    const int  eff  = len_pos - (excl ? 1 : 0);
    const float up  = u_pos[i];
    int u = (int)(up * (float)eff);        // fp32 multiply, trunc toward zero
    u = min(u, eff - 1);
    const int pos_idx = u + ((excl && (u >= i)) ? 1 : 0);

    // dst_pos = (sq_i - 2*dot) + sq_j  (same expression/order as all passing rounds)
    const float4 bp = *reinterpret_cast<const float4*>(hd + pos_idx * BD + lane * 4);
    float pp = a.x * bp.x + a.y * bp.y + a.z * bp.z + a.w * bp.w;
    const float dot_pos = wave_reduce_sum(pp);
    const float dst_pos = (sqi - 2.0f * dot_pos) + sq[pos_idx];

    // write anchor + positive rows now (overlaps with the scan)
    float* orow = out + i * (3 * BD);
    *reinterpret_cast<float4*>(orow + lane * 4) = a;
    *reinterpret_cast<float4*>(orow + BD + lane * 4) = bp;

    const float margin = margin_p[0];
    const float lnf    = (float)len_neg;
    const int   lnm1   = len_neg - 1;

    int   chosen = -1;
    float best   = __builtin_inff();
    int   best_c = 0;
    const float* unrow = u_neg + i * NTRIALS;

    // prologue: prefetch trials 0..5 into slots A..F
    int cA, cB, cC, cD, cE, cF;
    float4 bjA, bjB, bjC, bjD, bjE, bjF;
    float sqA, sqB, sqC, sqD, sqE, sqF;
#define PROLOGUE_SLOT(CS, BJS, SQS, T)                                          \
    {                                                                           \
        int c = (int)(unrow[T] * lnf);                                          \
        c = min(c, lnm1);                                                       \
        CS  = c;                                                                \
        BJS = *reinterpret_cast<const float4*>(hd + c * BD + lane * 4);         \
        SQS = sq[c];                                                            \
    }
    PROLOGUE_SLOT(cA, bjA, sqA, 0)
    PROLOGUE_SLOT(cB, bjB, sqB, 1)
    PROLOGUE_SLOT(cC, bjC, sqC, 2)
    PROLOGUE_SLOT(cD, bjD, sqD, 3)
    PROLOGUE_SLOT(cE, bjE, sqE, 4)
    PROLOGUE_SLOT(cF, bjF, sqF, 5)

    // main loop: t = 0,6,...,138 — computes trials t..t+5, prefetches t+6..t+11
    // (always in range; only branch is the wave-uniform group exit at the end)
    for (int t = 0; t < NTRIALS - 6; t += 6) {
        int cs0, cs1, cs2, cs3, cs4, cs5;
        float dn0, dn1, dn2, dn3, dn4, dn5;
        TRIAL_COMPUTE_PF(cA, bjA, sqA, t + 6,  cs0, dn0)
        TRIAL_COMPUTE_PF(cB, bjB, sqB, t + 7,  cs1, dn1)
        TRIAL_COMPUTE_PF(cC, bjC, sqC, t + 8,  cs2, dn2)
        TRIAL_COMPUTE_PF(cD, bjD, sqD, t + 9,  cs3, dn3)
        TRIAL_COMPUTE_PF(cE, bjE, sqE, t + 10, cs4, dn4)
        TRIAL_COMPUTE_PF(cF, bjF, sqF, t + 11, cs5, dn5)
        TRIAL_SEL(cs0, dn0)
        TRIAL_SEL(cs1, dn1)
        TRIAL_SEL(cs2, dn2)
        TRIAL_SEL(cs3, dn3)
        TRIAL_SEL(cs4, dn4)
        TRIAL_SEL(cs5, dn5)
        if (chosen >= 0) goto done;   // wave-uniform: chosen identical on all lanes
    }
    // peeled final group: trials 144..149 — no prefetch
    {
        int cs0, cs1, cs2, cs3, cs4, cs5;
        float dn0, dn1, dn2, dn3, dn4, dn5;
        TRIAL_COMPUTE_NP(cA, bjA, sqA, cs0, dn0)
        TRIAL_COMPUTE_NP(cB, bjB, sqB, cs1, dn1)
        TRIAL_COMPUTE_NP(cC, bjC, sqC, cs2, dn2)
        TRIAL_COMPUTE_NP(cD, bjD, sqD, cs3, dn3)
        TRIAL_COMPUTE_NP(cE, bjE, sqE, cs4, dn4)
        TRIAL_COMPUTE_NP(cF, bjF, sqF, cs5, dn5)
        TRIAL_SEL(cs0, dn0)
        TRIAL_SEL(cs1, dn1)
        TRIAL_SEL(cs2, dn2)
        TRIAL_SEL(cs3, dn3)
        TRIAL_SEL(cs4, dn4)
        TRIAL_SEL(cs5, dn5)
    }
done:
    ;
    const int neg = (chosen >= 0) ? chosen : best_c;

    const float4 bn = *reinterpret_cast<const float4*>(hd + neg * BD + lane * 4);
    *reinterpret_cast<float4*>(orow + 2 * BD + lane * 4) = bn;
}

extern "C" void kernel_launch(void* const* d_in, const int* in_sizes, int n_in,
                              void* d_out, int out_size, void* d_ws, size_t ws_size,
                              hipStream_t stream) {
    const float* hd     = (const float*)d_in[0];
    const int*   tgt    = (const int*)d_in[1];
    const float* margin = (const float*)d_in[2];
    const float* u_pos  = (const float*)d_in[3];
    const float* u_neg  = (const float*)d_in[4];
    float* out = (float*)d_out;

    float* sq  = (float*)d_ws;
    int*   cnt = (int*)((char*)d_ws + BN * sizeof(float));

    count_genuine_kernel<<<1, 1024, 0, stream>>>(tgt, cnt);
    sqnorm_kernel<<<BN / 4, 256, 0, stream>>>(hd, sq);
    triplet_kernel<<<BN / 4, 256, 0, stream>>>(hd, tgt, margin, u_pos, u_neg, sq, cnt, out);
}

// Round 11
// 88.571 us; speedup vs baseline: 1.1407x; 1.1374x over previous
//
#include <hip/hip_runtime.h>

#define BN 8192
#define BD 256
#define NTRIALS 150
#define HALF 75

// EXACT reduce from all six passing rounds.
__device__ __forceinline__ float wave_reduce_sum(float v) {
    #pragma unroll
    for (int m = 32; m > 0; m >>= 1) v += __shfl_xor(v, m, 64);
    return v;
}

// Kernel 1: count genuine (tgt == 0). Single block. (verbatim from passing rounds)
__global__ __launch_bounds__(1024) void count_genuine_kernel(
    const int* __restrict__ tgt, int* __restrict__ cnt)
{
    __shared__ int lds[16];
    const int t = threadIdx.x;
    int c = 0;
    for (int i = t; i < BN; i += 1024) c += (tgt[i] == 0) ? 1 : 0;
    #pragma unroll
    for (int m = 32; m > 0; m >>= 1) c += __shfl_xor(c, m, 64);
    if ((t & 63) == 0) lds[t >> 6] = c;
    __syncthreads();
    if (t == 0) {
        int s = 0;
        #pragma unroll
        for (int w = 0; w < 16; ++w) s += lds[w];
        *cnt = s;
    }
}

// Kernel 2: sq[i] = sum_d hd[i][d]^2. One wave per row. (verbatim from passing rounds)
__global__ __launch_bounds__(256) void sqnorm_kernel(
    const float* __restrict__ hd, float* __restrict__ sq)
{
    const int lane = threadIdx.x & 63;
    const int row  = blockIdx.x * 4 + (threadIdx.x >> 6);
    const float4 a = *reinterpret_cast<const float4*>(hd + row * BD + lane * 4);
    float s = a.x * a.x + a.y * a.y + a.z * a.z + a.w * a.w;
    s = wave_reduce_sum(s);
    if (lane == 0) sq[row] = s;
}

// Compute one trial's dn — BYTE-IDENTICAL text to passing R8/R9/R10.
#define TRIAL_COMPUTE_PF(CSLOT, BJSLOT, SQSLOT, PFT, CSAVE, DNSAVE)             \
    {                                                                           \
        const int    c_  = CSLOT;                                               \
        const float4 bj  = BJSLOT;                                              \
        const float  sqc = SQSLOT;                                              \
        {                                                                       \
            int c2 = (int)(unrow[PFT] * lnf);                                   \
            c2 = min(c2, lnm1);                                                 \
            CSLOT  = c2;                                                        \
            BJSLOT = *reinterpret_cast<const float4*>(hd + c2 * BD + lane * 4); \
            SQSLOT = sq[c2];                                                    \
        }                                                                       \
        float p = a.x * bj.x + a.y * bj.y + a.z * bj.z + a.w * bj.w;            \
        const float dn = (sqi - 2.0f * wave_reduce_sum(p)) + sqc;               \
        CSAVE  = c_;                                                            \
        DNSAVE = dn;                                                            \
    }

// Same compute text, no prefetch (final peeled group). (verbatim)
#define TRIAL_COMPUTE_NP(CSLOT, BJSLOT, SQSLOT, CSAVE, DNSAVE)                  \
    {                                                                           \
        const int    c_  = CSLOT;                                               \
        const float4 bj  = BJSLOT;                                              \
        const float  sqc = SQSLOT;                                              \
        float p = a.x * bj.x + a.y * bj.y + a.z * bj.z + a.w * bj.w;            \
        const float dn = (sqi - 2.0f * wave_reduce_sum(p)) + sqc;               \
        CSAVE  = c_;                                                            \
        DNSAVE = dn;                                                            \
    }

// In-order break / strict-< argmin — BYTE-IDENTICAL text to passing R8.
#define TRIAL_CHECK(CSAVE, DNSAVE)                                              \
    {                                                                           \
        const float z = dst_pos - (DNSAVE);                                     \
        if ((z < 0.0f) && (z + margin > 0.0f)) { chosen = (CSAVE); goto done; } \
        if ((DNSAVE) < best) { best = (DNSAVE); best_c = (CSAVE); }             \
    }

#define PROLOGUE_SLOT(CS, BJS, SQS, T)                                          \
    {                                                                           \
        int c = (int)(unrow[T] * lnf);                                          \
        c = min(c, lnm1);                                                       \
        CS  = c;                                                                \
        BJS = *reinterpret_cast<const float4*>(hd + c * BD + lane * 4);         \
        SQS = sq[c];                                                            \
    }

// Kernel 3: TWO waves per anchor — wave A scans trials 0..74, wave B 75..149.
// Each half runs R8's proven 3-deep grouped scan with per-trial early exit.
// Combine: A-hit > B-hit > strict-< argmin with tie -> A (first occurrence).
__global__ __launch_bounds__(256) void triplet_kernel(
    const float* __restrict__ hd, const int* __restrict__ tgt,
    const float* __restrict__ margin_p, const float* __restrict__ u_pos,
    const float* __restrict__ u_neg, const float* __restrict__ sq,
    const int* __restrict__ cnt, float* __restrict__ out)
{
    __shared__ int   s_chosen[2][2];
    __shared__ float s_best[2][2];
    __shared__ int   s_bestc[2][2];
    __shared__ int   s_aflag[2];

    const int lane = threadIdx.x & 63;
    const int w    = threadIdx.x >> 6;
    const int ancl = w >> 1;     // local anchor 0/1
    const int half = w & 1;      // 0: trials 0-74, 1: trials 75-149
    const int i    = blockIdx.x * 2 + ancl;

    if (threadIdx.x < 2) s_aflag[threadIdx.x] = 0;
    __syncthreads();

    // anchor row in registers (float4 per lane: 64*4 = 256 = D)
    const float4 a = *reinterpret_cast<const float4*>(hd + i * BD + lane * 4);
    const float sqi = sq[i];

    const int ng = *cnt;
    const int ti = tgt[i];
    const int len_pos = (ti == 0) ? ng : (BN - ng);
    const int len_neg = (ti == 0) ? (BN - ng) : ng;

    // positive index — exact integer/fp32 replication of the reference
    const bool excl = (i < len_pos);
    const int  eff  = len_pos - (excl ? 1 : 0);
    const float up  = u_pos[i];
    int u = (int)(up * (float)eff);        // fp32 multiply, trunc toward zero
    u = min(u, eff - 1);
    const int pos_idx = u + ((excl && (u >= i)) ? 1 : 0);

    // dst_pos = (sq_i - 2*dot) + sq_j  (same expression/order as all passing rounds;
    // computed redundantly in both halves -> identical bits -> consistent decisions)
    const float4 bp = *reinterpret_cast<const float4*>(hd + pos_idx * BD + lane * 4);
    float pp = a.x * bp.x + a.y * bp.y + a.z * bp.z + a.w * bp.w;
    const float dot_pos = wave_reduce_sum(pp);
    const float dst_pos = (sqi - 2.0f * dot_pos) + sq[pos_idx];

    float* orow = out + i * (3 * BD);
    if (half == 0) {   // anchor + positive rows; overlaps with the scan
        *reinterpret_cast<float4*>(orow + lane * 4) = a;
        *reinterpret_cast<float4*>(orow + BD + lane * 4) = bp;
    }

    const float margin = margin_p[0];
    const float lnf    = (float)len_neg;
    const int   lnm1   = len_neg - 1;

    int   chosen = -1;
    float best   = __builtin_inff();
    int   best_c = 0;
    const float* unrow = u_neg + i * NTRIALS + half * HALF;

    {
        // prologue: prefetch local trials 0,1,2 into slots A,B,C
        int cA, cB, cC; float4 bjA, bjB, bjC; float sqA, sqB, sqC;
        PROLOGUE_SLOT(cA, bjA, sqA, 0)
        PROLOGUE_SLOT(cB, bjB, sqB, 1)
        PROLOGUE_SLOT(cC, bjC, sqC, 2)

        // main loop: t = 0,3,...,69 — computes local trials t..t+2, prefetches t+3..t+5
        for (int t = 0; t < HALF - 3; t += 3) {
            int cs0, cs1, cs2;
            float dn0, dn1, dn2;
            TRIAL_COMPUTE_PF(cA, bjA, sqA, t + 3, cs0, dn0)
            TRIAL_COMPUTE_PF(cB, bjB, sqB, t + 4, cs1, dn1)
            TRIAL_COMPUTE_PF(cC, bjC, sqC, t + 5, cs2, dn2)
            TRIAL_CHECK(cs0, dn0)
            TRIAL_CHECK(cs1, dn1)
            TRIAL_CHECK(cs2, dn2)
            // B only: bail if A already hit (B's results are then discarded anyway)
            if (half && *(volatile int*)&s_aflag[ancl]) goto bail;
        }
        // peeled final group: local trials 72,73,74 — no prefetch
        {
            int cs0, cs1, cs2;
            float dn0, dn1, dn2;
            TRIAL_COMPUTE_NP(cA, bjA, sqA, cs0, dn0)
            TRIAL_COMPUTE_NP(cB, bjB, sqB, cs1, dn1)
            TRIAL_COMPUTE_NP(cC, bjC, sqC, cs2, dn2)
            TRIAL_CHECK(cs0, dn0)
            TRIAL_CHECK(cs1, dn1)
            TRIAL_CHECK(cs2, dn2)
        }
    }
done:
    if (half == 0 && chosen >= 0 && lane == 0) *(volatile int*)&s_aflag[ancl] = 1;
bail:
    if (lane == 0) {
        s_chosen[ancl][half] = chosen;
        s_best[ancl][half]   = best;
        s_bestc[ancl][half]  = best_c;
    }
    __syncthreads();

    if (half == 0) {
        const int chA = s_chosen[ancl][0];
        const int chB = s_chosen[ancl][1];
        int neg;
        if (chA >= 0) {
            neg = chA;                               // earliest hit: half A wins
        } else if (chB >= 0) {
            neg = chB;                               // hit only in half B
        } else {
            const float bA = s_best[ancl][0];
            const float bB = s_best[ancl][1];
            neg = (bB < bA) ? s_bestc[ancl][1]       // strict <: tie -> A (first occ.)
                            : s_bestc[ancl][0];
        }
        const float4 bn = *reinterpret_cast<const float4*>(hd + neg * BD + lane * 4);
        *reinterpret_cast<float4*>(orow + 2 * BD + lane * 4) = bn;
    }
}

extern "C" void kernel_launch(void* const* d_in, const int* in_sizes, int n_in,
                              void* d_out, int out_size, void* d_ws, size_t ws_size,
                              hipStream_t stream) {
    const float* hd     = (const float*)d_in[0];
    const int*   tgt    = (const int*)d_in[1];
    const float* margin = (const float*)d_in[2];
    const float* u_pos  = (const float*)d_in[3];
    const float* u_neg  = (const float*)d_in[4];
    float* out = (float*)d_out;

    float* sq  = (float*)d_ws;
    int*   cnt = (int*)((char*)d_ws + BN * sizeof(float));

    count_genuine_kernel<<<1, 1024, 0, stream>>>(tgt, cnt);
    sqnorm_kernel<<<BN / 4, 256, 0, stream>>>(hd, sq);
    triplet_kernel<<<BN / 2, 256, 0, stream>>>(hd, tgt, margin, u_pos, u_neg, sq, cnt, out);
}

// Round 12
// 80.055 us; speedup vs baseline: 1.2620x; 1.1064x over previous
//
#include <hip/hip_runtime.h>

#define BN 8192
#define BD 256
#define NTRIALS 150
#define HALF 75

// Butterfly reduce — identical tree/pairings/operand-order to the proven
// `for m in {32,16,8,4,2,1}: v += __shfl_xor(v,m,64)`, with fewer DS ops:
//   m=32: __shfl_xor (ds_bpermute)                 [proven]
//   m=16/8/4: ds_swizzle BitMode xor masks          [imm pattern, no addr VALU]
//   m=2/1: DPP quad_perm (pure VALU, no DS)
// All via builtins (no inline asm -> no register-aliasing hazard).
__device__ __forceinline__ float wave_reduce_sum(float v) {
    v += __shfl_xor(v, 32, 64);                                                  // lane ^ 32
    v += __int_as_float(__builtin_amdgcn_ds_swizzle(__float_as_int(v), 0x401F)); // lane ^ 16
    v += __int_as_float(__builtin_amdgcn_ds_swizzle(__float_as_int(v), 0x201F)); // lane ^ 8
    v += __int_as_float(__builtin_amdgcn_ds_swizzle(__float_as_int(v), 0x101F)); // lane ^ 4
    v += __int_as_float(__builtin_amdgcn_mov_dpp(__float_as_int(v), 0x4E, 0xF, 0xF, false)); // ^2
    v += __int_as_float(__builtin_amdgcn_mov_dpp(__float_as_int(v), 0xB1, 0xF, 0xF, false)); // ^1
    return v;
}

// Kernel 1: count genuine (tgt == 0). Single block. (int reduce — exact; verbatim)
__global__ __launch_bounds__(1024) void count_genuine_kernel(
    const int* __restrict__ tgt, int* __restrict__ cnt)
{
    __shared__ int lds[16];
    const int t = threadIdx.x;
    int c = 0;
    for (int i = t; i < BN; i += 1024) c += (tgt[i] == 0) ? 1 : 0;
    #pragma unroll
    for (int m = 32; m > 0; m >>= 1) c += __shfl_xor(c, m, 64);
    if ((t & 63) == 0) lds[t >> 6] = c;
    __syncthreads();
    if (t == 0) {
        int s = 0;
        #pragma unroll
        for (int w = 0; w < 16; ++w) s += lds[w];
        *cnt = s;
    }
}

// Kernel 2: sq[i] = sum_d hd[i][d]^2. One wave per row. (verbatim from passing rounds)
__global__ __launch_bounds__(256) void sqnorm_kernel(
    const float* __restrict__ hd, float* __restrict__ sq)
{
    const int lane = threadIdx.x & 63;
    const int row  = blockIdx.x * 4 + (threadIdx.x >> 6);
    const float4 a = *reinterpret_cast<const float4*>(hd + row * BD + lane * 4);
    float s = a.x * a.x + a.y * a.y + a.z * a.z + a.w * a.w;
    s = wave_reduce_sum(s);
    if (lane == 0) sq[row] = s;
}

// Compute one trial's dn — BYTE-IDENTICAL text to passing R8/R9/R10/R11.
#define TRIAL_COMPUTE_PF(CSLOT, BJSLOT, SQSLOT, PFT, CSAVE, DNSAVE)             \
    {                                                                           \
        const int    c_  = CSLOT;                                               \
        const float4 bj  = BJSLOT;                                              \
        const float  sqc = SQSLOT;                                              \
        {                                                                       \
            int c2 = (int)(unrow[PFT] * lnf);                                   \
            c2 = min(c2, lnm1);                                                 \
            CSLOT  = c2;                                                        \
            BJSLOT = *reinterpret_cast<const float4*>(hd + c2 * BD + lane * 4); \
            SQSLOT = sq[c2];                                                    \
        }                                                                       \
        float p = a.x * bj.x + a.y * bj.y + a.z * bj.z + a.w * bj.w;            \
        const float dn = (sqi - 2.0f * wave_reduce_sum(p)) + sqc;               \
        CSAVE  = c_;                                                            \
        DNSAVE = dn;                                                            \
    }

// Same compute text, no prefetch (final peeled group). (verbatim)
#define TRIAL_COMPUTE_NP(CSLOT, BJSLOT, SQSLOT, CSAVE, DNSAVE)                  \
    {                                                                           \
        const int    c_  = CSLOT;                                               \
        const float4 bj  = BJSLOT;                                              \
        const float  sqc = SQSLOT;                                              \
        float p = a.x * bj.x + a.y * bj.y + a.z * bj.z + a.w * bj.w;            \
        const float dn = (sqi - 2.0f * wave_reduce_sum(p)) + sqc;               \
        CSAVE  = c_;                                                            \
        DNSAVE = dn;                                                            \
    }

// In-order break / strict-< argmin — BYTE-IDENTICAL text to passing R8/R11.
#define TRIAL_CHECK(CSAVE, DNSAVE)                                              \
    {                                                                           \
        const float z = dst_pos - (DNSAVE);                                     \
        if ((z < 0.0f) && (z + margin > 0.0f)) { chosen = (CSAVE); goto done; } \
        if ((DNSAVE) < best) { best = (DNSAVE); best_c = (CSAVE); }             \
    }

#define PROLOGUE_SLOT(CS, BJS, SQS, T)                                          \
    {                                                                           \
        int c = (int)(unrow[T] * lnf);                                          \
        c = min(c, lnm1);                                                       \
        CS  = c;                                                                \
        BJS = *reinterpret_cast<const float4*>(hd + c * BD + lane * 4);         \
        SQS = sq[c];                                                            \
    }

// Kernel 3: TWO waves per anchor — wave A scans trials 0..74, wave B 75..149.
// (verbatim structure from passing R11)
__global__ __launch_bounds__(256) void triplet_kernel(
    const float* __restrict__ hd, const int* __restrict__ tgt,
    const float* __restrict__ margin_p, const float* __restrict__ u_pos,
    const float* __restrict__ u_neg, const float* __restrict__ sq,
    const int* __restrict__ cnt, float* __restrict__ out)
{
    __shared__ int   s_chosen[2][2];
    __shared__ float s_best[2][2];
    __shared__ int   s_bestc[2][2];
    __shared__ int   s_aflag[2];

    const int lane = threadIdx.x & 63;
    const int w    = threadIdx.x >> 6;
    const int ancl = w >> 1;     // local anchor 0/1
    const int half = w & 1;      // 0: trials 0-74, 1: trials 75-149
    const int i    = blockIdx.x * 2 + ancl;

    if (threadIdx.x < 2) s_aflag[threadIdx.x] = 0;
    __syncthreads();

    // anchor row in registers (float4 per lane: 64*4 = 256 = D)
    const float4 a = *reinterpret_cast<const float4*>(hd + i * BD + lane * 4);
    const float sqi = sq[i];

    const int ng = *cnt;
    const int ti = tgt[i];
    const int len_pos = (ti == 0) ? ng : (BN - ng);
    const int len_neg = (ti == 0) ? (BN - ng) : ng;

    // positive index — exact integer/fp32 replication of the reference
    const bool excl = (i < len_pos);
    const int  eff  = len_pos - (excl ? 1 : 0);
    const float up  = u_pos[i];
    int u = (int)(up * (float)eff);        // fp32 multiply, trunc toward zero
    u = min(u, eff - 1);
    const int pos_idx = u + ((excl && (u >= i)) ? 1 : 0);

    // dst_pos = (sq_i - 2*dot) + sq_j  (same expression/order as all passing rounds;
    // computed redundantly in both halves -> identical bits -> consistent decisions)
    const float4 bp = *reinterpret_cast<const float4*>(hd + pos_idx * BD + lane * 4);
    float pp = a.x * bp.x + a.y * bp.y + a.z * bp.z + a.w * bp.w;
    const float dot_pos = wave_reduce_sum(pp);
    const float dst_pos = (sqi - 2.0f * dot_pos) + sq[pos_idx];

    float* orow = out + i * (3 * BD);
    if (half == 0) {   // anchor + positive rows; overlaps with the scan
        *reinterpret_cast<float4*>(orow + lane * 4) = a;
        *reinterpret_cast<float4*>(orow + BD + lane * 4) = bp;
    }

    const float margin = margin_p[0];
    const float lnf    = (float)len_neg;
    const int   lnm1   = len_neg - 1;

    int   chosen = -1;
    float best   = __builtin_inff();
    int   best_c = 0;
    const float* unrow = u_neg + i * NTRIALS + half * HALF;

    {
        // prologue: prefetch local trials 0,1,2 into slots A,B,C
        int cA, cB, cC; float4 bjA, bjB, bjC; float sqA, sqB, sqC;
        PROLOGUE_SLOT(cA, bjA, sqA, 0)
        PROLOGUE_SLOT(cB, bjB, sqB, 1)
        PROLOGUE_SLOT(cC, bjC, sqC, 2)

        // main loop: t = 0,3,...,69 — computes local trials t..t+2, prefetches t+3..t+5
        for (int t = 0; t < HALF - 3; t += 3) {
            int cs0, cs1, cs2;
            float dn0, dn1, dn2;
            TRIAL_COMPUTE_PF(cA, bjA, sqA, t + 3, cs0, dn0)
            TRIAL_COMPUTE_PF(cB, bjB, sqB, t + 4, cs1, dn1)
            TRIAL_COMPUTE_PF(cC, bjC, sqC, t + 5, cs2, dn2)
            TRIAL_CHECK(cs0, dn0)
            TRIAL_CHECK(cs1, dn1)
            TRIAL_CHECK(cs2, dn2)
            // B only: bail if A already hit (B's results are then discarded anyway)
            if (half && *(volatile int*)&s_aflag[ancl]) goto bail;
        }
        // peeled final group: local trials 72,73,74 — no prefetch
        {
            int cs0, cs1, cs2;
            float dn0, dn1, dn2;
            TRIAL_COMPUTE_NP(cA, bjA, sqA, cs0, dn0)
            TRIAL_COMPUTE_NP(cB, bjB, sqB, cs1, dn1)
            TRIAL_COMPUTE_NP(cC, bjC, sqC, cs2, dn2)
            TRIAL_CHECK(cs0, dn0)
            TRIAL_CHECK(cs1, dn1)
            TRIAL_CHECK(cs2, dn2)
        }
    }
done:
    if (half == 0 && chosen >= 0 && lane == 0) *(volatile int*)&s_aflag[ancl] = 1;
bail:
    if (lane == 0) {
        s_chosen[ancl][half] = chosen;
        s_best[ancl][half]   = best;
        s_bestc[ancl][half]  = best_c;
    }
    __syncthreads();

    if (half == 0) {
        const int chA = s_chosen[ancl][0];
        const int chB = s_chosen[ancl][1];
        int neg;
        if (chA >= 0) {
            neg = chA;                               // earliest hit: half A wins
        } else if (chB >= 0) {
            neg = chB;                               // hit only in half B
        } else {
            const float bA = s_best[ancl][0];
            const float bB = s_best[ancl][1];
            neg = (bB < bA) ? s_bestc[ancl][1]       // strict <: tie -> A (first occ.)
                            : s_bestc[ancl][0];
        }
        const float4 bn = *reinterpret_cast<const float4*>(hd + neg * BD + lane * 4);
        *reinterpret_cast<float4*>(orow + 2 * BD + lane * 4) = bn;
    }
}

extern "C" void kernel_launch(void* const* d_in, const int* in_sizes, int n_in,
                              void* d_out, int out_size, void* d_ws, size_t ws_size,
                              hipStream_t stream) {
    const float* hd     = (const float*)d_in[0];
    const int*   tgt    = (const int*)d_in[1];
    const float* margin = (const float*)d_in[2];
    const float* u_pos  = (const float*)d_in[3];
    const float* u_neg  = (const float*)d_in[4];
    float* out = (float*)d_out;

    float* sq  = (float*)d_ws;
    int*   cnt = (int*)((char*)d_ws + BN * sizeof(float));

    count_genuine_kernel<<<1, 1024, 0, stream>>>(tgt, cnt);
    sqnorm_kernel<<<BN / 4, 256, 0, stream>>>(hd, sq);
    triplet_kernel<<<BN / 2, 256, 0, stream>>>(hd, tgt, margin, u_pos, u_neg, sq, cnt, out);
}

// Round 14
// 76.969 us; speedup vs baseline: 1.3126x; 1.0401x over previous
//
#include <hip/hip_runtime.h>

#define BN 8192
#define BD 256
#define NTRIALS 150
#define HALF 75

// EXACT R12 reduce (PASSED at 80.1 µs): shfl^32 + swizzle^16/^8/^4 + DPP^2/^1.
__device__ __forceinline__ float wave_reduce_sum(float v) {
    v += __shfl_xor(v, 32, 64);                                                  // lane ^ 32
    v += __int_as_float(__builtin_amdgcn_ds_swizzle(__float_as_int(v), 0x401F)); // lane ^ 16
    v += __int_as_float(__builtin_amdgcn_ds_swizzle(__float_as_int(v), 0x201F)); // lane ^ 8
    v += __int_as_float(__builtin_amdgcn_ds_swizzle(__float_as_int(v), 0x101F)); // lane ^ 4
    v += __int_as_float(__builtin_amdgcn_mov_dpp(__float_as_int(v), 0x4E, 0xF, 0xF, false)); // ^2
    v += __int_as_float(__builtin_amdgcn_mov_dpp(__float_as_int(v), 0xB1, 0xF, 0xF, false)); // ^1
    return v;
}

// Kernel 1: count genuine (tgt == 0). Single block. (verbatim)
__global__ __launch_bounds__(1024) void count_genuine_kernel(
    const int* __restrict__ tgt, int* __restrict__ cnt)
{
    __shared__ int lds[16];
    const int t = threadIdx.x;
    int c = 0;
    for (int i = t; i < BN; i += 1024) c += (tgt[i] == 0) ? 1 : 0;
    #pragma unroll
    for (int m = 32; m > 0; m >>= 1) c += __shfl_xor(c, m, 64);
    if ((t & 63) == 0) lds[t >> 6] = c;
    __syncthreads();
    if (t == 0) {
        int s = 0;
        #pragma unroll
        for (int w = 0; w < 16; ++w) s += lds[w];
        *cnt = s;
    }
}

// Kernel 2: sq[i] = sum_d hd[i][d]^2. One wave per row. (verbatim from R12)
__global__ __launch_bounds__(256) void sqnorm_kernel(
    const float* __restrict__ hd, float* __restrict__ sq)
{
    const int lane = threadIdx.x & 63;
    const int row  = blockIdx.x * 4 + (threadIdx.x >> 6);
    const float4 a = *reinterpret_cast<const float4*>(hd + row * BD + lane * 4);
    float s = a.x * a.x + a.y * a.y + a.z * a.z + a.w * a.w;
    s = wave_reduce_sum(s);
    if (lane == 0) sq[row] = s;
}

// Compute one trial's dn — R12 text + ONE change: readfirstlane(c2).
// c2 is wave-uniform (uniform inputs, identical per-lane ops), so
// readfirstlane is a bit-exact identity; it moves the index to SGPR so the
// sq[] load scalarizes and the row gather uses an SGPR base (saves ~10
// VALU/trial of 64-bit vector address arithmetic).
#define TRIAL_COMPUTE_PF(CSLOT, BJSLOT, SQSLOT, PFT, CSAVE, DNSAVE)             \
    {                                                                           \
        const int    c_  = CSLOT;                                               \
        const float4 bj  = BJSLOT;                                              \
        const float  sqc = SQSLOT;                                              \
        {                                                                       \
            int c2 = (int)(unrow[PFT] * lnf);                                   \
            c2 = min(c2, lnm1);                                                 \
            c2 = __builtin_amdgcn_readfirstlane(c2);                            \
            CSLOT  = c2;                                                        \
            BJSLOT = *reinterpret_cast<const float4*>(hd + c2 * BD + lane * 4); \
            SQSLOT = sq[c2];                                                    \
        }                                                                       \
        float p = a.x * bj.x + a.y * bj.y + a.z * bj.z + a.w * bj.w;            \
        const float dn = (sqi - 2.0f * wave_reduce_sum(p)) + sqc;               \
        CSAVE  = c_;                                                            \
        DNSAVE = dn;                                                            \
    }

// Same compute text, no prefetch (final peeled group). (verbatim from R12)
#define TRIAL_COMPUTE_NP(CSLOT, BJSLOT, SQSLOT, CSAVE, DNSAVE)                  \
    {                                                                           \
        const int    c_  = CSLOT;                                               \
        const float4 bj  = BJSLOT;                                              \
        const float  sqc = SQSLOT;                                              \
        float p = a.x * bj.x + a.y * bj.y + a.z * bj.z + a.w * bj.w;            \
        const float dn = (sqi - 2.0f * wave_reduce_sum(p)) + sqc;               \
        CSAVE  = c_;                                                            \
        DNSAVE = dn;                                                            \
    }

// In-order break / strict-< argmin — BYTE-IDENTICAL text to passing R8/R11/R12.
#define TRIAL_CHECK(CSAVE, DNSAVE)                                              \
    {                                                                           \
        const float z = dst_pos - (DNSAVE);                                     \
        if ((z < 0.0f) && (z + margin > 0.0f)) { chosen = (CSAVE); goto done; } \
        if ((DNSAVE) < best) { best = (DNSAVE); best_c = (CSAVE); }             \
    }

#define PROLOGUE_SLOT(CS, BJS, SQS, T)                                          \
    {                                                                           \
        int c = (int)(unrow[T] * lnf);                                          \
        c = min(c, lnm1);                                                       \
        c = __builtin_amdgcn_readfirstlane(c);                                  \
        CS  = c;                                                                \
        BJS = *reinterpret_cast<const float4*>(hd + c * BD + lane * 4);         \
        SQS = sq[c];                                                            \
    }

// Kernel 3: TWO waves per anchor — wave A scans trials 0..74, wave B 75..149.
// (verbatim structure from passing R11/R12)
__global__ __launch_bounds__(256) void triplet_kernel(
    const float* __restrict__ hd, const int* __restrict__ tgt,
    const float* __restrict__ margin_p, const float* __restrict__ u_pos,
    const float* __restrict__ u_neg, const float* __restrict__ sq,
    const int* __restrict__ cnt, float* __restrict__ out)
{
    __shared__ int   s_chosen[2][2];
    __shared__ float s_best[2][2];
    __shared__ int   s_bestc[2][2];
    __shared__ int   s_aflag[2];

    const int lane = threadIdx.x & 63;
    const int w    = threadIdx.x >> 6;
    const int ancl = w >> 1;     // local anchor 0/1
    const int half = w & 1;      // 0: trials 0-74, 1: trials 75-149
    const int i    = blockIdx.x * 2 + ancl;

    if (threadIdx.x < 2) s_aflag[threadIdx.x] = 0;
    __syncthreads();

    // anchor row in registers (float4 per lane: 64*4 = 256 = D)
    const float4 a = *reinterpret_cast<const float4*>(hd + i * BD + lane * 4);
    const float sqi = sq[i];

    const int ng = *cnt;
    const int ti = tgt[i];
    const int len_pos = (ti == 0) ? ng : (BN - ng);
    const int len_neg = (ti == 0) ? (BN - ng) : ng;

    // positive index — exact integer/fp32 replication of the reference
    const bool excl = (i < len_pos);
    const int  eff  = len_pos - (excl ? 1 : 0);
    const float up  = u_pos[i];
    int u = (int)(up * (float)eff);        // fp32 multiply, trunc toward zero
    u = min(u, eff - 1);
    const int pos_idx = u + ((excl && (u >= i)) ? 1 : 0);

    // dst_pos = (sq_i - 2*dot) + sq_j  (same expression/order as all passing rounds;
    // computed redundantly in both halves -> identical bits -> consistent decisions)
    const float4 bp = *reinterpret_cast<const float4*>(hd + pos_idx * BD + lane * 4);
    float pp = a.x * bp.x + a.y * bp.y + a.z * bp.z + a.w * bp.w;
    const float dot_pos = wave_reduce_sum(pp);
    const float dst_pos = (sqi - 2.0f * dot_pos) + sq[pos_idx];

    float* orow = out + i * (3 * BD);
    if (half == 0) {   // anchor + positive rows; overlaps with the scan
        *reinterpret_cast<float4*>(orow + lane * 4) = a;
        *reinterpret_cast<float4*>(orow + BD + lane * 4) = bp;
    }

    const float margin = margin_p[0];
    const float lnf    = (float)len_neg;
    const int   lnm1   = len_neg - 1;

    int   chosen = -1;
    float best   = __builtin_inff();
    int   best_c = 0;
    const float* unrow = u_neg + i * NTRIALS + half * HALF;

    {
        // prologue: prefetch local trials 0,1,2 into slots A,B,C
        int cA, cB, cC; float4 bjA, bjB, bjC; float sqA, sqB, sqC;
        PROLOGUE_SLOT(cA, bjA, sqA, 0)
        PROLOGUE_SLOT(cB, bjB, sqB, 1)
        PROLOGUE_SLOT(cC, bjC, sqC, 2)

        // main loop: t = 0,3,...,69 — computes local trials t..t+2, prefetches t+3..t+5
        for (int t = 0; t < HALF - 3; t += 3) {
            int cs0, cs1, cs2;
            float dn0, dn1, dn2;
            TRIAL_COMPUTE_PF(cA, bjA, sqA, t + 3, cs0, dn0)
            TRIAL_COMPUTE_PF(cB, bjB, sqB, t + 4, cs1, dn1)
            TRIAL_COMPUTE_PF(cC, bjC, sqC, t + 5, cs2, dn2)
            TRIAL_CHECK(cs0, dn0)
            TRIAL_CHECK(cs1, dn1)
            TRIAL_CHECK(cs2, dn2)
            // B only: bail if A already hit (B's results are then discarded anyway)
            if (half && *(volatile int*)&s_aflag[ancl]) goto bail;
        }
        // peeled final group: local trials 72,73,74 — no prefetch
        {
            int cs0, cs1, cs2;
            float dn0, dn1, dn2;
            TRIAL_COMPUTE_NP(cA, bjA, sqA, cs0, dn0)
            TRIAL_COMPUTE_NP(cB, bjB, sqB, cs1, dn1)
            TRIAL_COMPUTE_NP(cC, bjC, sqC, cs2, dn2)
            TRIAL_CHECK(cs0, dn0)
            TRIAL_CHECK(cs1, dn1)
            TRIAL_CHECK(cs2, dn2)
        }
    }
done:
    if (half == 0 && chosen >= 0 && lane == 0) *(volatile int*)&s_aflag[ancl] = 1;
bail:
    if (lane == 0) {
        s_chosen[ancl][half] = chosen;
        s_best[ancl][half]   = best;
        s_bestc[ancl][half]  = best_c;
    }
    __syncthreads();

    if (half == 0) {
        const int chA = s_chosen[ancl][0];
        const int chB = s_chosen[ancl][1];
        int neg;
        if (chA >= 0) {
            neg = chA;                               // earliest hit: half A wins
        } else if (chB >= 0) {
            neg = chB;                               // hit only in half B
        } else {
            const float bA = s_best[ancl][0];
            const float bB = s_best[ancl][1];
            neg = (bB < bA) ? s_bestc[ancl][1]       // strict <: tie -> A (first occ.)
                            : s_bestc[ancl][0];
        }
        const float4 bn = *reinterpret_cast<const float4*>(hd + neg * BD + lane * 4);
        *reinterpret_cast<float4*>(orow + 2 * BD + lane * 4) = bn;
    }
}

extern "C" void kernel_launch(void* const* d_in, const int* in_sizes, int n_in,
                              void* d_out, int out_size, void* d_ws, size_t ws_size,
                              hipStream_t stream) {
    const float* hd     = (const float*)d_in[0];
    const int*   tgt    = (const int*)d_in[1];
    const float* margin = (const float*)d_in[2];
    const float* u_pos  = (const float*)d_in[3];
    const float* u_neg  = (const float*)d_in[4];
    float* out = (float*)d_out;

    float* sq  = (float*)d_ws;
    int*   cnt = (int*)((char*)d_ws + BN * sizeof(float));

    count_genuine_kernel<<<1, 1024, 0, stream>>>(tgt, cnt);
    sqnorm_kernel<<<BN / 4, 256, 0, stream>>>(hd, sq);
    triplet_kernel<<<BN / 2, 256, 0, stream>>>(hd, tgt, margin, u_pos, u_neg, sq, cnt, out);
}